// Round 1
// baseline (1324.968 us; speedup 1.0000x reference)
//
#include <hip/hip_runtime.h>

// fuzzyConv: B=32, H=W=256, C=32, R=8, O=16, 3x3 VALID -> H'=W'=254
//
// exponent_r(pixel) = sum_{ki,kj,c} [ (-0.5*s2)*x^2 + (s2*mu)*x ] + K_r
//   s2 = sigma^2, K_r = -0.5 * sum s2*mu^2
// phi = exp(exponent); append residual rule; normalize; out = phi_norm @ cb (9x16)

#define CIN 32
#define HH  256
#define WW  256
#define HO  254
#define WO  254
#define BB  32
#define OO  16

// ---------------- prep: fold sigma/mu into interleaved weight table ----------------
// wv layout: 72 groups (tap(9) x c4(8)), each 64 floats:
//   group g = tap*8 + c4 ; within: cl(0..3)*16 + { r(0..7): w0, 8+r: w1 }
//   w0 = -0.5*sigma^2 ; w1 = sigma^2 * mu[r][c]
// Kc[8] appended after 72*64 floats.
__global__ __launch_bounds__(256) void prep_kernel(const float* __restrict__ sigma,
                                                   const float* __restrict__ mu,
                                                   float* __restrict__ wv,
                                                   float* __restrict__ Kc) {
    const int tid = threadIdx.x;
    for (int item = tid; item < 9 * CIN; item += 256) {
        const int tap = item >> 5;   // item / 32
        const int c   = item & 31;
        const int c4  = c >> 2, cl = c & 3;
        const int base = ((tap * 8 + c4) * 4 + cl) * 16;
#pragma unroll
        for (int r = 0; r < 8; ++r) {
            const float sg = sigma[item * 8 + r];
            const float s2 = sg * sg;
            wv[base + r]     = -0.5f * s2;
            wv[base + 8 + r] = s2 * mu[r * CIN + c];
        }
    }
    if (tid < 8) {
        const int r = tid;
        float k = 0.f;
        for (int item = 0; item < 9 * CIN; ++item) {
            const int c = item & 31;
            const float sg = sigma[item * 8 + r];
            const float m  = mu[r * CIN + c];
            k = fmaf(sg * sg, m * m, k);
        }
        Kc[r] = -0.5f * k;
    }
}

// ---------------- main kernel ----------------
// 1 thread -> 4 adjacent output pixels along W (all 8 rules).
// Block 256 threads = 4 rows x 64 j-chunks. Grid = B * 64 row-bands.
// Edge tiles clamp their start (duplicate compute of identical values).
__global__ __launch_bounds__(256) void fuzzy_main(const float* __restrict__ x,
                                                  const float* __restrict__ wv,
                                                  const float* __restrict__ Kc,
                                                  const float* __restrict__ residual,
                                                  const float* __restrict__ cb,
                                                  float* __restrict__ out) {
    const int tid = threadIdx.x;
    const int b   = blockIdx.x >> 6;
    const int ib  = blockIdx.x & 63;
    const int i   = min(4 * ib, HO - 4) + (tid >> 6);
    const int j0  = min(4 * (tid & 63), WO - 4);

    float acc[4][8];
#pragma unroll
    for (int t = 0; t < 4; ++t)
#pragma unroll
        for (int r = 0; r < 8; ++r)
            acc[t][r] = Kc[r];                     // uniform -> s_load, hoisted

#pragma unroll 1
    for (int ki = 0; ki < 3; ++ki) {
        const float* px = x + (((size_t)b * HH + (size_t)(i + ki)) * WW + (size_t)j0) * CIN;
#pragma unroll 1
        for (int c4 = 0; c4 < 8; ++c4) {
            // sliding x window: 6 pixel-positions x 4 channels
            float4 xb[6], x2b[6];
#pragma unroll
            for (int t = 0; t < 6; ++t) {
                const float4 v = *reinterpret_cast<const float4*>(px + t * CIN + c4 * 4);
                xb[t]  = v;
                x2b[t] = make_float4(v.x * v.x, v.y * v.y, v.z * v.z, v.w * v.w);
            }
            const float* wg = wv + (ki * 3 * 8 + c4) * 64;   // group base for kj=0
#pragma unroll
            for (int kj = 0; kj < 3; ++kj) {
                const float* w = wg + kj * 8 * 64;
#pragma unroll
                for (int cl = 0; cl < 4; ++cl) {
                    float w0[8], w1[8];                      // uniform -> SGPRs
#pragma unroll
                    for (int r = 0; r < 8; ++r) {
                        w0[r] = w[cl * 16 + r];
                        w1[r] = w[cl * 16 + 8 + r];
                    }
#pragma unroll
                    for (int t = 0; t < 4; ++t) {
                        const float xs  = ((const float*)&xb[t + kj])[cl];
                        const float x2s = ((const float*)&x2b[t + kj])[cl];
#pragma unroll
                        for (int r = 0; r < 8; ++r) {
                            acc[t][r] = fmaf(w0[r], x2s, acc[t][r]);
                            acc[t][r] = fmaf(w1[r], xs,  acc[t][r]);
                        }
                    }
                }
            }
        }
    }

    // epilogue: exp, normalize with residual rule, 9x16 consequent matvec
    const float res   = residual[0];
    const float sbase = res + 1e-9f;
#pragma unroll 1
    for (int t = 0; t < 4; ++t) {
        float phi[8];
        float s = sbase;
#pragma unroll
        for (int r = 0; r < 8; ++r) { phi[r] = __expf(acc[t][r]); s += phi[r]; }
        const float inv = 1.0f / s;
        float* op = out + (((size_t)b * HO + (size_t)i) * WO + (size_t)(j0 + t)) * OO;
#pragma unroll
        for (int o4 = 0; o4 < 4; ++o4) {
            float4 v;
#pragma unroll
            for (int q = 0; q < 4; ++q) {
                const int o = o4 * 4 + q;
                float a = res * cb[8 * OO + o];
#pragma unroll
                for (int r = 0; r < 8; ++r) a = fmaf(phi[r], cb[r * OO + o], a);
                ((float*)&v)[q] = a * inv;
            }
            *reinterpret_cast<float4*>(op + o4 * 4) = v;
        }
    }
}

extern "C" void kernel_launch(void* const* d_in, const int* in_sizes, int n_in,
                              void* d_out, int out_size, void* d_ws, size_t ws_size,
                              hipStream_t stream) {
    const float* x     = (const float*)d_in[0];
    const float* sigma = (const float*)d_in[1];   // (3,3,32,8)
    const float* mu    = (const float*)d_in[2];   // (8,32)
    const float* resid = (const float*)d_in[3];   // (1,)
    const float* cb    = (const float*)d_in[4];   // (9,16)
    float* outp = (float*)d_out;

    float* wv = (float*)d_ws;          // 72*64 floats
    float* Kc = wv + 72 * 64;          // 8 floats

    hipLaunchKernelGGL(prep_kernel, dim3(1), dim3(256), 0, stream, sigma, mu, wv, Kc);
    hipLaunchKernelGGL(fuzzy_main, dim3(BB * 64), dim3(256), 0, stream,
                       x, wv, Kc, resid, cb, outp);
}

// Round 2
// 322.907 us; speedup vs baseline: 4.1032x; 4.1032x over previous
//
#include <hip/hip_runtime.h>

// fuzzyConv: B=32, H=W=256, C=32, R=8, O=16, 3x3 VALID -> H'=W'=254
//
// exponent_r(pixel) = sum_{ki,kj,c} [ (-0.5*s2)*x^2 + (s2*mu)*x ] + K_r
//   s2 = sigma^2, K_r = -0.5 * sum s2*mu^2
// phi = exp(exponent); append residual rule; normalize; out = phi_norm @ cb (9x16)

#define CIN 32
#define HH  256
#define WW  256
#define HO  254
#define WO  254
#define BB  32
#define OO  16

#define TW 64              // output tile width
#define TH 4               // output tile height
#define LROWS (TH + 2)     // 6 staged input rows
#define LPIX  (TW + 2)     // 66 staged pixels per row
#define LCHUNK (LPIX * 8)  // 528 16-B chunks per row (8 chunks/pixel)

// ---------------- prep: fold sigma/mu into interleaved weight table ----------------
// wv layout: 72 groups (tap(9) x c4(8)), each 64 floats:
//   group g = tap*8 + c4 ; within: cl(0..3)*16 + { r(0..7): w0, 8+r: w1 }
//   w0 = -0.5*sigma^2 ; w1 = sigma^2 * mu[r][c]
__global__ __launch_bounds__(256) void prep_kernel(const float* __restrict__ sigma,
                                                   const float* __restrict__ mu,
                                                   float* __restrict__ wv,
                                                   float* __restrict__ Kc) {
    const int tid = threadIdx.x;
    for (int item = tid; item < 9 * CIN; item += 256) {
        const int tap = item >> 5;   // item / 32
        const int c   = item & 31;
        const int c4  = c >> 2, cl = c & 3;
        const int base = ((tap * 8 + c4) * 4 + cl) * 16;
#pragma unroll
        for (int r = 0; r < 8; ++r) {
            const float sg = sigma[item * 8 + r];
            const float s2 = sg * sg;
            wv[base + r]     = -0.5f * s2;
            wv[base + 8 + r] = s2 * mu[r * CIN + c];
        }
    }
    if (tid < 8) {
        const int r = tid;
        float k = 0.f;
        for (int item = 0; item < 9 * CIN; ++item) {
            const int c = item & 31;
            const float sg = sigma[item * 8 + r];
            const float m  = mu[r * CIN + c];
            k = fmaf(sg * sg, m * m, k);
        }
        Kc[r] = -0.5f * k;
    }
}

// ---------------- main kernel ----------------
// Block 256 threads -> 4x64 output tile, 1 pixel/thread.
// Stage (TH+2) x (TW+2) x 32C input tile in LDS (coalesced float4, XOR-swizzled
// so compute-phase ds_read_b128 at 128B pixel stride is bank-conflict-free).
__global__ __launch_bounds__(256) void fuzzy_main(const float* __restrict__ x,
                                                  const float* __restrict__ wv,
                                                  const float* __restrict__ Kc,
                                                  const float* __restrict__ residual,
                                                  const float* __restrict__ cb,
                                                  float* __restrict__ out) {
    __shared__ float4 lds4[LROWS * LCHUNK];   // 50688 B

    const int tid = threadIdx.x;
    const int jt  = blockIdx.x;               // 0..3
    const int it  = blockIdx.y;               // 0..63
    const int b   = blockIdx.z;               // 0..31
    const int i0  = min(TH * it, HO - TH);    // clamped tile origin (dup compute at edge)
    const int j0  = min(TW * jt, WO - TW);

    // ---- stage: 6 rows x 66 pixels x 32C, coalesced, swizzled ----
#pragma unroll 1
    for (int row = 0; row < LROWS; ++row) {
        const float4* src = reinterpret_cast<const float4*>(
            x + (((size_t)b * HH + (size_t)(i0 + row)) * WW + (size_t)j0) * CIN);
        float4* dst = lds4 + row * LCHUNK;
        for (int f = tid; f < LCHUNK; f += 256) {
            const int pixel = f >> 3, c4 = f & 7;
            dst[(pixel << 3) | (c4 ^ (pixel & 7))] = src[f];
        }
    }
    __syncthreads();

    // ---- compute: 1 output pixel per thread ----
    const int rr = tid >> 6;                  // 0..3 (tile row; wave-uniform)
    const int j  = tid & 63;                  // 0..63 (lane -> tile col)

    float acc[8];
#pragma unroll
    for (int r = 0; r < 8; ++r) acc[r] = Kc[r];   // uniform -> s_load

#pragma unroll 1
    for (int ki = 0; ki < 3; ++ki) {
        const float4* lrow = lds4 + (rr + ki) * LCHUNK;
#pragma unroll 1
        for (int kj = 0; kj < 3; ++kj) {
            const int pixel = j + kj;
            const float4* pbase = lrow + (pixel << 3);
            const int sw = pixel & 7;
            const float* wt = wv + (size_t)((ki * 3 + kj) * 8) * 64;
#pragma unroll 1
            for (int c4 = 0; c4 < 8; ++c4) {
                const float4 v = pbase[c4 ^ sw];
                const float vx[4] = { v.x, v.y, v.z, v.w };
                const float v2[4] = { v.x * v.x, v.y * v.y, v.z * v.z, v.w * v.w };
                const float* w = wt + c4 * 64;
#pragma unroll
                for (int cl = 0; cl < 4; ++cl) {
                    float w0[8], w1[8];                  // uniform -> SGPRs
#pragma unroll
                    for (int r = 0; r < 8; ++r) {
                        w0[r] = w[cl * 16 + r];
                        w1[r] = w[cl * 16 + 8 + r];
                    }
#pragma unroll
                    for (int r = 0; r < 8; ++r) {
                        acc[r] = fmaf(w0[r], v2[cl], acc[r]);
                        acc[r] = fmaf(w1[r], vx[cl], acc[r]);
                    }
                }
            }
        }
    }

    // ---- epilogue: exp, normalize with residual rule, 9x16 consequent matvec ----
    const float res = residual[0];
    float phi[8];
    float s = res + 1e-9f;
#pragma unroll
    for (int r = 0; r < 8; ++r) { phi[r] = __expf(acc[r]); s += phi[r]; }
    const float inv = 1.0f / s;

    float* op = out + (((size_t)b * HO + (size_t)(i0 + rr)) * WO + (size_t)(j0 + j)) * OO;
#pragma unroll
    for (int o4 = 0; o4 < 4; ++o4) {
        float4 v;
#pragma unroll
        for (int q = 0; q < 4; ++q) {
            const int o = o4 * 4 + q;
            float a = res * cb[8 * OO + o];
#pragma unroll
            for (int r = 0; r < 8; ++r) a = fmaf(phi[r], cb[r * OO + o], a);
            ((float*)&v)[q] = a * inv;
        }
        *reinterpret_cast<float4*>(op + o4 * 4) = v;
    }
}

extern "C" void kernel_launch(void* const* d_in, const int* in_sizes, int n_in,
                              void* d_out, int out_size, void* d_ws, size_t ws_size,
                              hipStream_t stream) {
    const float* x     = (const float*)d_in[0];
    const float* sigma = (const float*)d_in[1];   // (3,3,32,8)
    const float* mu    = (const float*)d_in[2];   // (8,32)
    const float* resid = (const float*)d_in[3];   // (1,)
    const float* cb    = (const float*)d_in[4];   // (9,16)
    float* outp = (float*)d_out;

    float* wv = (float*)d_ws;          // 72*64 floats
    float* Kc = wv + 72 * 64;          // 8 floats

    hipLaunchKernelGGL(prep_kernel, dim3(1), dim3(256), 0, stream, sigma, mu, wv, Kc);
    hipLaunchKernelGGL(fuzzy_main, dim3(4, 64, BB), dim3(256), 0, stream,
                       x, wv, Kc, resid, cb, outp);
}

// Round 3
// 159.297 us; speedup vs baseline: 8.3176x; 2.0271x over previous
//
#include <hip/hip_runtime.h>
#include <hip/hip_bf16.h>

// fuzzyConv: B=32, H=W=256, C=32, R=8, O=16, 3x3 VALID -> H'=W'=254
// Premise as implicit GEMM on matrix cores:
//   exponent_r(p) = sum_k A[p,k] * W[k,r] + K_r,   k = (tap,ch,{x^2,x}), K=576
//   A in bf16 (staged features), W in bf16 (precomputed B-fragments), acc fp32.
// Then fp32 epilogue: exp, residual-normalize, 9x16 consequent matvec.

#define CIN 32
#define HH  256
#define WW  256
#define HO  254
#define WO  254
#define BB  32
#define OO  16

#define TW 64
#define TH 4
#define LROWS 6                    // TH+2 staged input rows
#define LPIX 66                    // TW+2 staged pixels per row
#define ROWCH (LPIX * 8)           // 528 16-B chunks per row (8 chunks/pixel)
#define LDS_CHUNKS (LROWS * ROWCH) // 3168 chunks = 50688 B

typedef __attribute__((ext_vector_type(8))) short short8;   // 8 bf16 (4 VGPR)
typedef __attribute__((ext_vector_type(4))) float f32x4;

static __device__ __forceinline__ unsigned short f2bf(float f) {
    __hip_bfloat16 h = __float2bfloat16(f);
    return *reinterpret_cast<unsigned short*>(&h);
}

// ---------------- prep: B-fragments + K constants ----------------
// wb: 18 frags (tap*2+khalf) x 64 lanes x 8 bf16.
// B[k_local, n]: lane l -> n = l&15 (rule, 0 if n>=8), k_local = (l>>4)*8 + e.
// global k within tap = khalf*32 + k_local ; c = k>>1 ; feat = k&1.
// feat==0 -> weight = -0.5*sigma^2 (multiplies x^2); feat==1 -> sigma^2*mu (multiplies x).
__global__ __launch_bounds__(256) void prep_kernel(const float* __restrict__ sigma,
                                                   const float* __restrict__ mu,
                                                   unsigned short* __restrict__ wb,
                                                   float* __restrict__ Kc) {
    const int tid = threadIdx.x;
    for (int item = tid; item < 18 * 64; item += 256) {
        const int frag = item >> 6;          // 0..17
        const int lane = item & 63;
        const int tap = frag >> 1, khalf = frag & 1;
        const int n = lane & 15, g = lane >> 4;
#pragma unroll
        for (int e = 0; e < 8; ++e) {
            float wgt = 0.f;
            if (n < 8) {
                const int cfeat = khalf * 32 + g * 8 + e;
                const int c = cfeat >> 1;
                const float sg = sigma[(tap * CIN + c) * 8 + n];   // (3,3,C,R)
                const float s2 = sg * sg;
                wgt = (cfeat & 1) ? s2 * mu[n * CIN + c] : -0.5f * s2;
            }
            wb[item * 8 + e] = f2bf(wgt);
        }
    }
    if (tid < 8) {
        const int r = tid;
        float k = 0.f;
        for (int item = 0; item < 9 * CIN; ++item) {
            const int c = item & 31;
            const float sg = sigma[item * 8 + r];
            const float m = mu[r * CIN + c];
            k = fmaf(sg * sg, m * m, k);
        }
        Kc[r] = -0.5f * k;
    }
}

// ---------------- main kernel ----------------
// Block 256 = 4 waves; wave w owns output row (i0+w), 64 pixels = 4 M-tiles of 16.
// LDS: 6 rows x 66 px x 64 bf16 features [x^2,x interleaved], XOR-swizzled chunks.
__global__ __launch_bounds__(256, 3) void fuzzy_main(const float* __restrict__ x,
                                                     const unsigned short* __restrict__ wb,
                                                     const float* __restrict__ Kc,
                                                     const float* __restrict__ residual,
                                                     const float* __restrict__ cb,
                                                     float* __restrict__ out) {
    __shared__ float4 lds4[LDS_CHUNKS];     // 50688 B
    short8* ldsS = reinterpret_cast<short8*>(lds4);

    const int tid = threadIdx.x;
    const int jt = blockIdx.x;              // 0..3
    const int it = blockIdx.y;              // 0..63
    const int b  = blockIdx.z;              // 0..31
    const int i0 = min(TH * it, HO - TH);   // clamped (edge tiles duplicate compute)
    const int j0 = min(TW * jt, WO - TW);

    // ---- stage: fp32 -> bf16 features, coalesced, swizzled ----
#pragma unroll 1
    for (int f = tid; f < LDS_CHUNKS; f += 256) {
        const int row = f / ROWCH;          // const-divisor -> magic mul
        const int rem = f - row * ROWCH;    // 0..527
        const float4 v = reinterpret_cast<const float4*>(
            x + (((size_t)b * HH + (size_t)(i0 + row)) * WW + (size_t)j0) * CIN)[rem];
        const int pixel = rem >> 3, c4 = rem & 7;
        short8 s;
        s[0] = f2bf(v.x * v.x); s[1] = f2bf(v.x);
        s[2] = f2bf(v.y * v.y); s[3] = f2bf(v.y);
        s[4] = f2bf(v.z * v.z); s[5] = f2bf(v.z);
        s[6] = f2bf(v.w * v.w); s[7] = f2bf(v.w);
        ldsS[row * ROWCH + (pixel << 3) + (c4 ^ (pixel & 7))] = s;
    }

    const int lane = tid & 63;

    // ---- B-fragments resident in VGPRs (coalesced 16B/lane loads) ----
    short8 Bf[18];
#pragma unroll
    for (int q = 0; q < 18; ++q) Bf[q] = reinterpret_cast<const short8*>(wb)[q * 64 + lane];

    __syncthreads();

    const int wv_ = tid >> 6;               // wave id = tile row
    const int m = lane & 15, g = lane >> 4; // A-frag: pixel-in-tile, k-group

    // per-lane chunk offsets for each (kj, khalf); (mt*16 + m + kj)&7 == (m+kj)&7
    int bc[3][2];
#pragma unroll
    for (int kj = 0; kj < 3; ++kj) {
        const int mk = m + kj;
        bc[kj][0] = mk * 8 + (g ^ (mk & 7));
        bc[kj][1] = mk * 8 + ((g + 4) ^ (mk & 7));
    }

    f32x4 acc[4];
#pragma unroll
    for (int mt = 0; mt < 4; ++mt) acc[mt] = (f32x4){0.f, 0.f, 0.f, 0.f};

    const short8* baseS = ldsS + wv_ * ROWCH;
#pragma unroll
    for (int ki = 0; ki < 3; ++ki) {
#pragma unroll
        for (int kj = 0; kj < 3; ++kj) {
            const int tap = ki * 3 + kj;
#pragma unroll
            for (int mt = 0; mt < 4; ++mt) {
                const short8 a0 = baseS[ki * ROWCH + mt * 128 + bc[kj][0]];
                acc[mt] = __builtin_amdgcn_mfma_f32_16x16x32_bf16(a0, Bf[2 * tap], acc[mt], 0, 0, 0);
            }
#pragma unroll
            for (int mt = 0; mt < 4; ++mt) {
                const short8 a1 = baseS[ki * ROWCH + mt * 128 + bc[kj][1]];
                acc[mt] = __builtin_amdgcn_mfma_f32_16x16x32_bf16(a1, Bf[2 * tap + 1], acc[mt], 0, 0, 0);
            }
        }
    }

    // ---- per-wave transpose via LDS: D[pixel, rule] -> lane-owns-pixel ----
    __syncthreads();                        // all waves done reading features
    float* eps = reinterpret_cast<float*>(lds4) + wv_ * 512;   // 64 px x 8 rules
    if (m < 8) {
#pragma unroll
        for (int mt = 0; mt < 4; ++mt)
#pragma unroll
            for (int e = 0; e < 4; ++e)
                eps[(mt * 16 + g * 4 + e) * 8 + m] = acc[mt][e];
    }
    __syncthreads();

    // ---- fp32 epilogue: exp, residual-normalize, consequent matvec ----
    const float res = residual[0];
    const float* ep = reinterpret_cast<float*>(lds4) + wv_ * 512 + lane * 8;
    float ph[8];
    float ssum = res + 1e-9f;
#pragma unroll
    for (int r = 0; r < 8; ++r) { ph[r] = __expf(ep[r] + Kc[r]); ssum += ph[r]; }
    const float inv = 1.0f / ssum;

    float* op = out + (((size_t)b * HO + (size_t)(i0 + wv_)) * WO + (size_t)(j0 + lane)) * OO;
#pragma unroll
    for (int o4 = 0; o4 < 4; ++o4) {
        float4 v;
#pragma unroll
        for (int q = 0; q < 4; ++q) {
            const int o = o4 * 4 + q;
            float a = res * cb[8 * OO + o];
#pragma unroll
            for (int r = 0; r < 8; ++r) a = fmaf(ph[r], cb[r * OO + o], a);
            ((float*)&v)[q] = a * inv;
        }
        *reinterpret_cast<float4*>(op + o4 * 4) = v;
    }
}

extern "C" void kernel_launch(void* const* d_in, const int* in_sizes, int n_in,
                              void* d_out, int out_size, void* d_ws, size_t ws_size,
                              hipStream_t stream) {
    const float* x     = (const float*)d_in[0];
    const float* sigma = (const float*)d_in[1];   // (3,3,32,8)
    const float* mu    = (const float*)d_in[2];   // (8,32)
    const float* resid = (const float*)d_in[3];   // (1,)
    const float* cb    = (const float*)d_in[4];   // (9,16)
    float* outp = (float*)d_out;

    float* Kc = (float*)d_ws;                          // 8 floats
    unsigned short* wb = (unsigned short*)(Kc + 8);    // 18*64*8 bf16 = 18432 B

    hipLaunchKernelGGL(prep_kernel, dim3(1), dim3(256), 0, stream, sigma, mu, wb, Kc);
    hipLaunchKernelGGL(fuzzy_main, dim3(4, 64, BB), dim3(256), 0, stream,
                       x, wb, Kc, resid, cb, outp);
}

// Round 4
// 121.316 us; speedup vs baseline: 10.9216x; 1.3131x over previous
//
#include <hip/hip_runtime.h>

// fuzzyConv: B=32, H=W=256, C=32, R=8, O=16, 3x3 VALID -> H'=W'=254
// Premise as implicit GEMM on matrix cores (fp16 features, fp32 accum):
//   exponent_r(p) = sum_{tap,c} [ (s2*mu)[tap,c,r]*x + (-0.5*s2)[tap,c,r]*x^2 ] + K_r
// LDS holds only x (fp16, 64B/pixel); x^2 fragment derived in-register via v_pk_mul_f16.
// Then fp32 epilogue: exp, residual-normalize, 9x16 consequent matvec.

#define CIN 32
#define HH  256
#define WW  256
#define HO  254
#define WO  254
#define BB  32
#define OO  16

#define TW 64
#define TH 4
#define LROWS 6                     // TH+2 staged input rows
#define LPIX 66                     // TW+2 staged pixels per row
#define ROWCH (LPIX * 4)            // 264 16-B chunks per row (4 chunks/pixel, 8 fp16 ch each)
#define LDS_CHUNKS (LROWS * ROWCH)  // 1584 chunks = 25344 B
#define STAGE_ITERS 7               // ceil(1584/256)

typedef _Float16 half8 __attribute__((ext_vector_type(8)));   // 8 fp16 (4 VGPR)
typedef __attribute__((ext_vector_type(4))) float f32x4;

static __device__ __forceinline__ unsigned short f2h(float f) {
    _Float16 h = (_Float16)f;
    return *reinterpret_cast<unsigned short*>(&h);
}

// ---------------- prep: B-fragments (fp16) + K constants ----------------
// wb: 18 frags = tap(9) x ftype(2); ftype0 pairs with x (w = s2*mu),
// ftype1 pairs with x^2 (w = -0.5*s2). K-index = channel: lane l -> n=l&15,
// g=l>>4, element e -> channel c = g*8+e. n>=8 -> 0 (pad rules).
__global__ __launch_bounds__(256) void prep_kernel(const float* __restrict__ sigma,
                                                   const float* __restrict__ mu,
                                                   unsigned short* __restrict__ wb,
                                                   float* __restrict__ Kc) {
    const int tid = threadIdx.x;
    for (int item = tid; item < 18 * 64; item += 256) {
        const int frag = item >> 6;          // 0..17
        const int lane = item & 63;
        const int tap = frag >> 1, ftype = frag & 1;
        const int n = lane & 15, g = lane >> 4;
#pragma unroll
        for (int e = 0; e < 8; ++e) {
            float wgt = 0.f;
            if (n < 8) {
                const int c = g * 8 + e;
                const float sg = sigma[(tap * CIN + c) * 8 + n];   // (3,3,C,R)
                const float s2 = sg * sg;
                wgt = ftype ? -0.5f * s2 : s2 * mu[n * CIN + c];
            }
            wb[item * 8 + e] = f2h(wgt);
        }
    }
    if (tid < 8) {
        const int r = tid;
        float k = 0.f;
        for (int item = 0; item < 9 * CIN; ++item) {
            const int c = item & 31;
            const float sg = sigma[item * 8 + r];
            const float m = mu[r * CIN + c];
            k = fmaf(sg * sg, m * m, k);
        }
        Kc[r] = -0.5f * k;
    }
}

// ---------------- main kernel ----------------
// Block 256 = 4 waves; wave w owns output row (i0+w), 64 px = 4 M-tiles of 16.
// LDS: 6 rows x 66 px x 32ch fp16 x, chunk-swizzled (g ^ (px&3)).
__global__ __launch_bounds__(256, 4) void fuzzy_main(const float* __restrict__ x,
                                                     const unsigned short* __restrict__ wb,
                                                     const float* __restrict__ Kc,
                                                     const float* __restrict__ residual,
                                                     const float* __restrict__ cb,
                                                     float* __restrict__ out) {
    __shared__ __align__(16) unsigned char ldsRaw[LDS_CHUNKS * 16];   // 25344 B
    half8* ldsH = reinterpret_cast<half8*>(ldsRaw);

    const int tid = threadIdx.x;
    const int jt = blockIdx.x;              // 0..3
    const int it = blockIdx.y;              // 0..63
    const int b  = blockIdx.z;              // 0..31
    const int i0 = min(TH * it, HO - TH);   // clamped (edge tiles duplicate compute)
    const int j0 = min(TW * jt, WO - TW);

    // ---- stage: issue ALL global loads first, then convert + swizzled LDS write ----
    float4 va[STAGE_ITERS], vb[STAGE_ITERS];
#pragma unroll
    for (int t = 0; t < STAGE_ITERS; ++t) {
        const int f = tid + t * 256;
        const int fc = min(f, LDS_CHUNKS - 1);
        const int row = fc / ROWCH;
        const int rem = fc - row * ROWCH;
        const float4* src = reinterpret_cast<const float4*>(
            x + (((size_t)b * HH + (size_t)(i0 + row)) * WW + (size_t)j0) * CIN);
        va[t] = src[2 * rem];
        vb[t] = src[2 * rem + 1];
    }
#pragma unroll
    for (int t = 0; t < STAGE_ITERS; ++t) {
        const int f = tid + t * 256;
        if (f < LDS_CHUNKS) {
            const int row = f / ROWCH;
            const int rem = f - row * ROWCH;
            const int px = rem >> 2, gg = rem & 3;
            half8 h;
            h[0] = (_Float16)va[t].x; h[1] = (_Float16)va[t].y;
            h[2] = (_Float16)va[t].z; h[3] = (_Float16)va[t].w;
            h[4] = (_Float16)vb[t].x; h[5] = (_Float16)vb[t].y;
            h[6] = (_Float16)vb[t].z; h[7] = (_Float16)vb[t].w;
            ldsH[row * ROWCH + (px << 2) + (gg ^ (px & 3))] = h;
        }
    }

    const int lane = tid & 63;

    // ---- B-fragments resident in VGPRs (18 x 4 VGPR) ----
    const half8* wbv = reinterpret_cast<const half8*>(wb);
    half8 Bf[18];
#pragma unroll
    for (int q = 0; q < 18; ++q) Bf[q] = wbv[q * 64 + lane];

    __syncthreads();

    const int wv_ = tid >> 6;               // wave id = tile row
    const int m = lane & 15, g = lane >> 4; // A-frag: pixel-in-tile, k-group (0..3)

    // per-lane chunk offset per kj (mt adds mt*64): pixel p = m+kj,
    // chunk = p*4 + (g ^ (p&3))
    int bc[3];
#pragma unroll
    for (int kj = 0; kj < 3; ++kj) {
        const int p = m + kj;
        bc[kj] = p * 4 + (g ^ (p & 3));
    }

    f32x4 acc[4];
#pragma unroll
    for (int mt = 0; mt < 4; ++mt) acc[mt] = (f32x4){0.f, 0.f, 0.f, 0.f};

    const half8* baseS = ldsH + wv_ * ROWCH;
#pragma unroll
    for (int ki = 0; ki < 3; ++ki) {
#pragma unroll
        for (int kj = 0; kj < 3; ++kj) {
            const int tap = ki * 3 + kj;
            half8 ax[4];
#pragma unroll
            for (int mt = 0; mt < 4; ++mt)
                ax[mt] = baseS[ki * ROWCH + mt * 64 + bc[kj]];
#pragma unroll
            for (int mt = 0; mt < 4; ++mt)
                acc[mt] = __builtin_amdgcn_mfma_f32_16x16x32_f16(ax[mt], Bf[2 * tap], acc[mt], 0, 0, 0);
#pragma unroll
            for (int mt = 0; mt < 4; ++mt) {
                const half8 ax2 = ax[mt] * ax[mt];           // v_pk_mul_f16 x4
                acc[mt] = __builtin_amdgcn_mfma_f32_16x16x32_f16(ax2, Bf[2 * tap + 1], acc[mt], 0, 0, 0);
            }
        }
    }

    // ---- per-wave transpose via LDS: D[pixel, rule] -> lane-owns-pixel ----
    __syncthreads();                        // all waves done reading features
    float* eps = reinterpret_cast<float*>(ldsRaw) + wv_ * 512;   // 64 px x 8 rules
    if (m < 8) {
#pragma unroll
        for (int mt = 0; mt < 4; ++mt)
#pragma unroll
            for (int e = 0; e < 4; ++e)
                eps[(mt * 16 + g * 4 + e) * 8 + m] = acc[mt][e];
    }
    __syncthreads();

    // ---- fp32 epilogue: exp, residual-normalize, consequent matvec ----
    const float res = residual[0];
    const float* ep = reinterpret_cast<float*>(ldsRaw) + wv_ * 512 + lane * 8;
    float ph[8];
    float ssum = res + 1e-9f;
#pragma unroll
    for (int r = 0; r < 8; ++r) { ph[r] = __expf(ep[r] + Kc[r]); ssum += ph[r]; }
    const float inv = 1.0f / ssum;

    float* op = out + (((size_t)b * HO + (size_t)(i0 + wv_)) * WO + (size_t)(j0 + lane)) * OO;
#pragma unroll
    for (int o4 = 0; o4 < 4; ++o4) {
        float4 v;
#pragma unroll
        for (int q = 0; q < 4; ++q) {
            const int o = o4 * 4 + q;
            float a = res * cb[8 * OO + o];
#pragma unroll
            for (int r = 0; r < 8; ++r) a = fmaf(ph[r], cb[r * OO + o], a);
            ((float*)&v)[q] = a * inv;
        }
        *reinterpret_cast<float4*>(op + o4 * 4) = v;
    }
}

extern "C" void kernel_launch(void* const* d_in, const int* in_sizes, int n_in,
                              void* d_out, int out_size, void* d_ws, size_t ws_size,
                              hipStream_t stream) {
    const float* x     = (const float*)d_in[0];
    const float* sigma = (const float*)d_in[1];   // (3,3,32,8)
    const float* mu    = (const float*)d_in[2];   // (8,32)
    const float* resid = (const float*)d_in[3];   // (1,)
    const float* cb    = (const float*)d_in[4];   // (9,16)
    float* outp = (float*)d_out;

    float* Kc = (float*)d_ws;                          // 8 floats
    unsigned short* wb = (unsigned short*)(Kc + 8);    // 18*64*8 fp16 = 18432 B

    hipLaunchKernelGGL(prep_kernel, dim3(1), dim3(256), 0, stream, sigma, mu, wb, Kc);
    hipLaunchKernelGGL(fuzzy_main, dim3(4, 64, BB), dim3(256), 0, stream,
                       x, wb, Kc, resid, cb, outp);
}